// Round 1
// baseline (364.284 us; speedup 1.0000x reference)
//
#include <hip/hip_runtime.h>
#include <cstdint>
#include <cstddef>

#define NTOK 8192
#define DIN  1024
#define DH   128
#define KVB  64

typedef __attribute__((ext_vector_type(4))) float f32x4;
typedef __bf16 bf16x8 __attribute__((ext_vector_type(8)));
typedef unsigned short u16x8 __attribute__((ext_vector_type(8)));

__device__ __forceinline__ unsigned short f2bf(float f){
  union { float f; unsigned u; } x; x.f = f;
  unsigned r = x.u + 0x7FFFu + ((x.u >> 16) & 1u);
  return (unsigned short)(r >> 16);
}
__device__ __forceinline__ float bf2f(unsigned short b){
  union { unsigned u; float f; } x; x.u = ((unsigned)b) << 16;
  return x.f;
}

// ---------- kernel 1: split W_{q,k,v} into hi/lo bf16, transposed to [384][1024]
__global__ void k_wsplit(const float* __restrict__ Wq, const float* __restrict__ Wk,
                         const float* __restrict__ Wv,
                         unsigned short* __restrict__ WhT, unsigned short* __restrict__ WlT){
  int e = blockIdx.x * 256 + threadIdx.x;   // 384*1024 threads
  int n = e >> 10, k = e & 1023;
  const float* W = (n < 128) ? Wq : ((n < 256) ? Wk : Wv);
  float v = W[(size_t)k * 128 + (n & 127)];
  unsigned short h = f2bf(v);
  WhT[e] = h;
  WlT[e] = f2bf(v - bf2f(h));
}

// ---------- kernel 2: QKV projection via bf16x2 MFMA.  grid (128, 3), 256 thr.
// Block computes 64 rows x 128 cols of one of Q/K/V. Waves 2x2, each 32m x 64n.
__global__ __launch_bounds__(256) void k_proj(const float* __restrict__ x,
    const unsigned short* __restrict__ WhT, const unsigned short* __restrict__ WlT,
    unsigned short* __restrict__ Qh, unsigned short* __restrict__ Ql,
    unsigned short* __restrict__ Kh, unsigned short* __restrict__ Kl,
    unsigned short* __restrict__ Vt){
  const int lane = threadIdx.x & 63, wid = threadIdx.x >> 6;
  const int wm = wid >> 1, wn = wid & 1;
  const int l15 = lane & 15, lk = lane >> 4;
  const int bm = blockIdx.x, bt = blockIdx.y;   // bt: 0=Q 1=K 2=V

  f32x4 acc[2][4] = {};

  const float* A0 = x + (size_t)(bm*64 + wm*32 + l15) * DIN + lk*8;
  const unsigned short* B0h = WhT + (size_t)(bt*128 + wn*64 + l15) * DIN + lk*8;
  const unsigned short* B0l = WlT + (size_t)(bt*128 + wn*64 + l15) * DIN + lk*8;

  for (int kc = 0; kc < DIN/32; ++kc){
    bf16x8 ah[2], al[2];
    #pragma unroll
    for (int mf = 0; mf < 2; ++mf){
      const float* p = A0 + (size_t)mf*16*DIN + kc*32;
      f32x4 v0 = *(const f32x4*)p;
      f32x4 v1 = *(const f32x4*)(p + 4);
      u16x8 hb, lb;
      #pragma unroll
      for (int j = 0; j < 4; ++j){
        unsigned short h0 = f2bf(v0[j]);
        hb[j] = h0; lb[j] = f2bf(v0[j] - bf2f(h0));
        unsigned short h1 = f2bf(v1[j]);
        hb[4+j] = h1; lb[4+j] = f2bf(v1[j] - bf2f(h1));
      }
      ah[mf] = __builtin_bit_cast(bf16x8, hb);
      al[mf] = __builtin_bit_cast(bf16x8, lb);
    }
    #pragma unroll
    for (int nf = 0; nf < 4; ++nf){
      bf16x8 bh = *(const bf16x8*)(const void*)(B0h + (size_t)nf*16*DIN + kc*32);
      bf16x8 bl = *(const bf16x8*)(const void*)(B0l + (size_t)nf*16*DIN + kc*32);
      #pragma unroll
      for (int mf = 0; mf < 2; ++mf){
        acc[mf][nf] = __builtin_amdgcn_mfma_f32_16x16x32_bf16(ah[mf], bh, acc[mf][nf], 0, 0, 0);
        acc[mf][nf] = __builtin_amdgcn_mfma_f32_16x16x32_bf16(ah[mf], bl, acc[mf][nf], 0, 0, 0);
        acc[mf][nf] = __builtin_amdgcn_mfma_f32_16x16x32_bf16(al[mf], bh, acc[mf][nf], 0, 0, 0);
      }
    }
  }

  const float qscale = 0.08838834764831845f;  // 1/sqrt(128), folded into Q
  #pragma unroll
  for (int mf = 0; mf < 2; ++mf){
    #pragma unroll
    for (int nf = 0; nf < 4; ++nf){
      #pragma unroll
      for (int r = 0; r < 4; ++r){
        int row = bm*64 + wm*32 + mf*16 + lk*4 + r;
        int col = wn*64 + nf*16 + l15;
        float v = acc[mf][nf][r];
        if (bt == 0){
          v *= qscale;
          unsigned short h = f2bf(v);
          Qh[(size_t)row*DH + col] = h;
          Ql[(size_t)row*DH + col] = f2bf(v - bf2f(h));
        } else if (bt == 1){
          unsigned short h = f2bf(v);
          Kh[(size_t)row*DH + col] = h;
          Kl[(size_t)row*DH + col] = f2bf(v - bf2f(h));
        } else {
          Vt[(size_t)col*NTOK + row] = f2bf(v);   // transposed V for PV B-fragments
        }
      }
    }
  }
}

// ---------- kernel 3: flash attention partials. grid 64*ksplit, 256 thr (4 waves x 32 q-rows).
__global__ __launch_bounds__(256, 2) void k_flash(
    const unsigned short* __restrict__ Qh, const unsigned short* __restrict__ Ql,
    const unsigned short* __restrict__ Kh, const unsigned short* __restrict__ Kl,
    const unsigned short* __restrict__ Vt,
    float* __restrict__ Opart, float* __restrict__ mpart, float* __restrict__ lpart,
    int ksplit){
  const int lane = threadIdx.x & 63, wid = threadIdx.x >> 6;
  const int l15 = lane & 15, lk = lane >> 4;
  const int qb = blockIdx.x / ksplit, ks = blockIdx.x % ksplit;
  const int q0 = qb*128 + wid*32;
  const int kvlen = NTOK / ksplit;
  const int kvbase = ks * kvlen;

  __shared__ unsigned short P[4][32][72];   // pad to 72 (144B rows): conflict-free b128 reads

  bf16x8 qh[2][4], ql[2][4];
  #pragma unroll
  for (int mf = 0; mf < 2; ++mf)
    #pragma unroll
    for (int kc = 0; kc < 4; ++kc){
      size_t off = (size_t)(q0 + mf*16 + l15)*DH + kc*32 + lk*8;
      qh[mf][kc] = *(const bf16x8*)(const void*)(Qh + off);
      ql[mf][kc] = *(const bf16x8*)(const void*)(Ql + off);
    }

  f32x4 o[2][8] = {};
  float m_run[2][4], l_run[2][4];
  #pragma unroll
  for (int mf = 0; mf < 2; ++mf)
    #pragma unroll
    for (int r = 0; r < 4; ++r){ m_run[mf][r] = -1e30f; l_run[mf][r] = 0.f; }

  for (int t = 0; t < kvlen / KVB; ++t){
    const int kv0 = kvbase + t*KVB;
    // ---- S = Q K^T (bf16x2: hh + hl + lh), pre-scaled via Q
    f32x4 s[2][4] = {};
    #pragma unroll
    for (int nf = 0; nf < 4; ++nf){
      #pragma unroll
      for (int kc = 0; kc < 4; ++kc){
        size_t koff = (size_t)(kv0 + nf*16 + l15)*DH + kc*32 + lk*8;
        bf16x8 kh = *(const bf16x8*)(const void*)(Kh + koff);
        bf16x8 kl = *(const bf16x8*)(const void*)(Kl + koff);
        #pragma unroll
        for (int mf = 0; mf < 2; ++mf){
          s[mf][nf] = __builtin_amdgcn_mfma_f32_16x16x32_bf16(qh[mf][kc], kh, s[mf][nf], 0,0,0);
          s[mf][nf] = __builtin_amdgcn_mfma_f32_16x16x32_bf16(qh[mf][kc], kl, s[mf][nf], 0,0,0);
          s[mf][nf] = __builtin_amdgcn_mfma_f32_16x16x32_bf16(ql[mf][kc], kh, s[mf][nf], 0,0,0);
        }
      }
    }
    // ---- online softmax (row = q: lane rows lk*4+r; kv spread over l15 and nf)
    #pragma unroll
    for (int mf = 0; mf < 2; ++mf){
      #pragma unroll
      for (int r = 0; r < 4; ++r){
        float mx = fmaxf(fmaxf(s[mf][0][r], s[mf][1][r]), fmaxf(s[mf][2][r], s[mf][3][r]));
        #pragma unroll
        for (int off = 1; off < 16; off <<= 1) mx = fmaxf(mx, __shfl_xor(mx, off));
        float mnew = fmaxf(m_run[mf][r], mx);
        float corr = __expf(m_run[mf][r] - mnew);
        float tsum = 0.f;
        #pragma unroll
        for (int nf = 0; nf < 4; ++nf){
          float p = __expf(s[mf][nf][r] - mnew);
          s[mf][nf][r] = p;
          tsum += p;
        }
        #pragma unroll
        for (int off = 1; off < 16; off <<= 1) tsum += __shfl_xor(tsum, off);
        m_run[mf][r] = mnew;
        l_run[mf][r] = l_run[mf][r]*corr + tsum;
        #pragma unroll
        for (int nd = 0; nd < 8; ++nd) o[mf][nd][r] *= corr;
      }
    }
    // ---- P -> LDS (bf16), per-wave buffer, no barrier needed
    #pragma unroll
    for (int mf = 0; mf < 2; ++mf)
      #pragma unroll
      for (int nf = 0; nf < 4; ++nf)
        #pragma unroll
        for (int r = 0; r < 4; ++r)
          P[wid][mf*16 + lk*4 + r][nf*16 + l15] = f2bf(s[mf][nf][r]);
    // ---- O += P V   (B-fragments contiguous from Vt[d][kv])
    #pragma unroll
    for (int kc = 0; kc < 2; ++kc){
      bf16x8 pa0 = *(const bf16x8*)(const void*)&P[wid][l15][kc*32 + lk*8];
      bf16x8 pa1 = *(const bf16x8*)(const void*)&P[wid][16 + l15][kc*32 + lk*8];
      #pragma unroll
      for (int nd = 0; nd < 8; ++nd){
        bf16x8 vt = *(const bf16x8*)(const void*)(Vt + (size_t)(nd*16 + l15)*NTOK + kv0 + kc*32 + lk*8);
        o[0][nd] = __builtin_amdgcn_mfma_f32_16x16x32_bf16(pa0, vt, o[0][nd], 0,0,0);
        o[1][nd] = __builtin_amdgcn_mfma_f32_16x16x32_bf16(pa1, vt, o[1][nd], 0,0,0);
      }
    }
  }

  float* Op = Opart + ((size_t)ks*NTOK + q0)*DH;
  #pragma unroll
  for (int mf = 0; mf < 2; ++mf)
    #pragma unroll
    for (int nd = 0; nd < 8; ++nd)
      #pragma unroll
      for (int r = 0; r < 4; ++r)
        Op[(size_t)(mf*16 + lk*4 + r)*DH + nd*16 + l15] = o[mf][nd][r];
  if (l15 == 0){
    #pragma unroll
    for (int mf = 0; mf < 2; ++mf)
      #pragma unroll
      for (int r = 0; r < 4; ++r){
        mpart[(size_t)ks*NTOK + q0 + mf*16 + lk*4 + r] = m_run[mf][r];
        lpart[(size_t)ks*NTOK + q0 + mf*16 + lk*4 + r] = l_run[mf][r];
      }
  }
}

// ---------- kernel 4: merge ksplit partials.  grid NTOK*32/256, 256 thr.
__global__ void k_merge(const float* __restrict__ Opart, const float* __restrict__ mpart,
                        const float* __restrict__ lpart, float* __restrict__ out, int ksplit){
  int gid = blockIdx.x*256 + threadIdx.x;   // NTOK*32
  int n = gid >> 5, c4 = (gid & 31) * 4;
  float M = -1e30f;
  for (int ks = 0; ks < ksplit; ++ks) M = fmaxf(M, mpart[(size_t)ks*NTOK + n]);
  float L = 0.f;
  f32x4 acc = {0.f, 0.f, 0.f, 0.f};
  for (int ks = 0; ks < ksplit; ++ks){
    float w = __expf(mpart[(size_t)ks*NTOK + n] - M);
    L += lpart[(size_t)ks*NTOK + n] * w;
    f32x4 op = *(const f32x4*)(Opart + ((size_t)ks*NTOK + n)*DH + c4);
    acc += op * w;
  }
  float inv = 1.f / L;
  *(f32x4*)(out + (size_t)n*DH + c4) = acc * inv;
}

extern "C" void kernel_launch(void* const* d_in, const int* in_sizes, int n_in,
                              void* d_out, int out_size, void* d_ws, size_t ws_size,
                              hipStream_t stream){
  const float* x  = (const float*)d_in[0];
  const float* Wq = (const float*)d_in[1];
  const float* Wk = (const float*)d_in[2];
  const float* Wv = (const float*)d_in[3];
  float* out = (float*)d_out;

  char* ws = (char*)d_ws;
  const size_t SZ_WT = (size_t)384*1024*2;      // 768 KB
  const size_t SZ_QK = (size_t)NTOK*DH*2;       // 2 MB
  size_t off = 0;
  unsigned short* WhT = (unsigned short*)(ws + off); off += SZ_WT;
  unsigned short* WlT = (unsigned short*)(ws + off); off += SZ_WT;
  unsigned short* Qh  = (unsigned short*)(ws + off); off += SZ_QK;
  unsigned short* Ql  = (unsigned short*)(ws + off); off += SZ_QK;
  unsigned short* Kh  = (unsigned short*)(ws + off); off += SZ_QK;
  unsigned short* Kl  = (unsigned short*)(ws + off); off += SZ_QK;
  unsigned short* Vt  = (unsigned short*)(ws + off); off += SZ_QK;

  int ksplit = 8;   // shrink if workspace is tight
  while (ksplit > 1 &&
         off + (size_t)ksplit*NTOK*DH*4 + 2*(size_t)ksplit*NTOK*4 > ws_size)
    ksplit >>= 1;
  float* Opart = (float*)(ws + off); off += (size_t)ksplit*NTOK*DH*4;
  float* mpart = (float*)(ws + off); off += (size_t)ksplit*NTOK*4;
  float* lpart = (float*)(ws + off); off += (size_t)ksplit*NTOK*4;

  k_wsplit<<<dim3((384*1024)/256), dim3(256), 0, stream>>>(Wq, Wk, Wv, WhT, WlT);
  k_proj  <<<dim3(NTOK/64, 3),      dim3(256), 0, stream>>>(x, WhT, WlT, Qh, Ql, Kh, Kl, Vt);
  k_flash <<<dim3((NTOK/128)*ksplit), dim3(256), 0, stream>>>(Qh, Ql, Kh, Kl, Vt,
                                                              Opart, mpart, lpart, ksplit);
  k_merge <<<dim3(NTOK*32/256), dim3(256), 0, stream>>>(Opart, mpart, lpart, out, ksplit);
}

// Round 2
// 249.548 us; speedup vs baseline: 1.4598x; 1.4598x over previous
//
#include <hip/hip_runtime.h>
#include <cstdint>
#include <cstddef>

#define NTOK 8192
#define DIN  1024
#define DH   128
#define KVB  64

typedef __attribute__((ext_vector_type(4))) float f32x4;
typedef __bf16 bf16x8 __attribute__((ext_vector_type(8)));
typedef unsigned short u16x8 __attribute__((ext_vector_type(8)));
typedef unsigned short u16x4 __attribute__((ext_vector_type(4)));

__device__ __forceinline__ unsigned short f2bf(float f){
  union { float f; unsigned u; } x; x.f = f;
  unsigned r = x.u + 0x7FFFu + ((x.u >> 16) & 1u);
  return (unsigned short)(r >> 16);
}
__device__ __forceinline__ float bf2f(unsigned short b){
  union { unsigned u; float f; } x; x.u = ((unsigned)b) << 16;
  return x.f;
}
// async global->LDS, 16B per lane. LDS dest = wave-uniform base + lane*16 (HW).
__device__ __forceinline__ void gload16(const void* g, void* l){
  using gp_t = const __attribute__((address_space(1))) char*;
  using lp_t = __attribute__((address_space(3))) char*;
  __builtin_amdgcn_global_load_lds((gp_t)(uintptr_t)g, (lp_t)(uint32_t)(uintptr_t)l, 16, 0, 0);
}

// ---------- kernel 1: split W into hi/lo bf16, transposed to [384][1024]
__global__ void k_wsplit(const float* __restrict__ Wq, const float* __restrict__ Wk,
                         const float* __restrict__ Wv,
                         unsigned short* __restrict__ WhT, unsigned short* __restrict__ WlT){
  int e = blockIdx.x * 256 + threadIdx.x;   // 384*1024 threads
  int n = e >> 10, k = e & 1023;
  const float* W = (n < 128) ? Wq : ((n < 256) ? Wk : Wv);
  float v = W[(size_t)k * 128 + (n & 127)];
  unsigned short h = f2bf(v);
  WhT[e] = h;
  WlT[e] = f2bf(v - bf2f(h));
}

// ---------- kernel 1b: split x into hi/lo bf16 (row-major [8192][1024])
__global__ void k_xsplit(const float* __restrict__ x,
                         unsigned short* __restrict__ xh, unsigned short* __restrict__ xl){
  size_t i = ((size_t)blockIdx.x * 256 + threadIdx.x) * 8;
  f32x4 a = *(const f32x4*)(x + i);
  f32x4 b = *(const f32x4*)(x + i + 4);
  u16x8 h, l;
  #pragma unroll
  for (int j = 0; j < 4; ++j){
    unsigned short h0 = f2bf(a[j]); h[j] = h0;   l[j]   = f2bf(a[j] - bf2f(h0));
    unsigned short h1 = f2bf(b[j]); h[4+j] = h1; l[4+j] = f2bf(b[j] - bf2f(h1));
  }
  *(u16x8*)(xh + i) = h;
  *(u16x8*)(xl + i) = l;
}

// ---------- kernel 2: QKV projection (bf16x2 MFMA, pre-split inputs). grid (128,3), 256 thr.
__global__ __launch_bounds__(256) void k_proj(
    const unsigned short* __restrict__ xh, const unsigned short* __restrict__ xl,
    const unsigned short* __restrict__ WhT, const unsigned short* __restrict__ WlT,
    unsigned short* __restrict__ Qh, unsigned short* __restrict__ Ql,
    unsigned short* __restrict__ Kh, unsigned short* __restrict__ Kl,
    unsigned short* __restrict__ Vt){
  const int lane = threadIdx.x & 63, wid = threadIdx.x >> 6;
  const int wm = wid >> 1, wn = wid & 1;
  const int l15 = lane & 15, lk = lane >> 4;
  const int bm = blockIdx.x, bt = blockIdx.y;   // bt: 0=Q 1=K 2=V

  f32x4 acc[2][4] = {};

  const unsigned short* Ah = xh + (size_t)(bm*64 + wm*32 + l15) * DIN + lk*8;
  const unsigned short* Al = xl + (size_t)(bm*64 + wm*32 + l15) * DIN + lk*8;
  const unsigned short* B0h = WhT + (size_t)(bt*128 + wn*64 + l15) * DIN + lk*8;
  const unsigned short* B0l = WlT + (size_t)(bt*128 + wn*64 + l15) * DIN + lk*8;

  for (int kc = 0; kc < DIN/32; ++kc){
    bf16x8 ah[2], al[2];
    #pragma unroll
    for (int mf = 0; mf < 2; ++mf){
      ah[mf] = *(const bf16x8*)(const void*)(Ah + (size_t)mf*16*DIN + kc*32);
      al[mf] = *(const bf16x8*)(const void*)(Al + (size_t)mf*16*DIN + kc*32);
    }
    #pragma unroll
    for (int nf = 0; nf < 4; ++nf){
      bf16x8 bh = *(const bf16x8*)(const void*)(B0h + (size_t)nf*16*DIN + kc*32);
      bf16x8 bl = *(const bf16x8*)(const void*)(B0l + (size_t)nf*16*DIN + kc*32);
      #pragma unroll
      for (int mf = 0; mf < 2; ++mf){
        acc[mf][nf] = __builtin_amdgcn_mfma_f32_16x16x32_bf16(ah[mf], bh, acc[mf][nf], 0, 0, 0);
        acc[mf][nf] = __builtin_amdgcn_mfma_f32_16x16x32_bf16(ah[mf], bl, acc[mf][nf], 0, 0, 0);
        acc[mf][nf] = __builtin_amdgcn_mfma_f32_16x16x32_bf16(al[mf], bh, acc[mf][nf], 0, 0, 0);
      }
    }
  }

  const float qscale = 0.08838834764831845f;  // 1/sqrt(128), folded into Q
  #pragma unroll
  for (int mf = 0; mf < 2; ++mf){
    #pragma unroll
    for (int nf = 0; nf < 4; ++nf){
      #pragma unroll
      for (int r = 0; r < 4; ++r){
        int row = bm*64 + wm*32 + mf*16 + lk*4 + r;
        int col = wn*64 + nf*16 + l15;
        float v = acc[mf][nf][r];
        if (bt == 0){
          v *= qscale;
          unsigned short h = f2bf(v);
          Qh[(size_t)row*DH + col] = h;
          Ql[(size_t)row*DH + col] = f2bf(v - bf2f(h));
        } else if (bt == 1){
          unsigned short h = f2bf(v);
          Kh[(size_t)row*DH + col] = h;
          Kl[(size_t)row*DH + col] = f2bf(v - bf2f(h));
        } else {
          Vt[(size_t)col*NTOK + row] = f2bf(v);   // V^T [128][8192]
        }
      }
    }
  }
}

// ---------- kernel 3: flash attention partials.
// 512 thr = 8 waves, each wave owns 16 q rows (BM=128). KVB=64.
// LDS 64KB: Kh[64][128]swz | Kl | Vt[128][64]swz | P[8][16][64]swz
// Swapped QK^T: S^T = K·Q^T, lane = one q column (l15), kv in-lane.
__global__ __launch_bounds__(512, 4) void k_flash(
    const unsigned short* __restrict__ Qh, const unsigned short* __restrict__ Ql,
    const unsigned short* __restrict__ Kh, const unsigned short* __restrict__ Kl,
    const unsigned short* __restrict__ Vt,
    float* __restrict__ Opart, float* __restrict__ mpart, float* __restrict__ lpart,
    int ksplit){
  __shared__ __align__(16) char smem[65536];
  const int tid = threadIdx.x;
  const int lane = tid & 63, wid = tid >> 6;
  const int l15 = lane & 15, lk = lane >> 4;
  const int qb = blockIdx.x / ksplit, ks = blockIdx.x - qb*ksplit;
  const int q0 = qb*128 + wid*16;
  const int kvlen = NTOK / ksplit;
  const int kvbase = ks * kvlen;
  const int NT = kvlen / KVB;

  char* Pbase = smem + 48*1024 + wid*2048;   // per-wave P [16][64] bf16, swizzled

  // Q fragments (B-operand): lane holds Q[q0+l15][kc*32+lk*8 .. +7]
  bf16x8 qh[4], ql[4];
  #pragma unroll
  for (int kc = 0; kc < 4; ++kc){
    size_t off = (size_t)(q0 + l15)*DH + kc*32 + lk*8;
    qh[kc] = *(const bf16x8*)(const void*)(Qh + off);
    ql[kc] = *(const bf16x8*)(const void*)(Ql + off);
  }

  // staging: wave w stages chunks 2w,2w+1 of each of Kh,Kl,Vt (1KB each).
  // K chunk i covers rows 4i..4i+3 of [64][128]; lane -> row 4i+(lane>>4), slot lane&15,
  //   fetches global chunk cg = slot ^ (row&7)  (inverse swizzle at source).
  const int i0 = 2*wid, i1 = 2*wid + 1;
  int rk0 = 4*i0 + (lane >> 4), rk1 = 4*i1 + (lane >> 4);
  int gk0 = rk0*DH + ((lane & 15) ^ (rk0 & 7))*8;
  int gk1 = rk1*DH + ((lane & 15) ^ (rk1 & 7))*8;
  // V chunk i covers rows 8i..8i+7 of [128][64]; lane -> row 8i+(lane>>3), slot lane&7
  int rv0 = 8*i0 + (lane >> 3), rv1 = 8*i1 + (lane >> 3);
  int gv0 = rv0*NTOK + ((lane & 7) ^ (rv0 & 7))*8;
  int gv1 = rv1*NTOK + ((lane & 7) ^ (rv1 & 7))*8;
  char* ldsK0 = smem + i0*1024;
  char* ldsK1 = smem + i1*1024;

  #define STAGE(kv0_) do {                                              \
    int _o = (kv0_)*DH;                                                 \
    gload16(Kh + (size_t)(_o + gk0), ldsK0);                            \
    gload16(Kh + (size_t)(_o + gk1), ldsK1);                            \
    gload16(Kl + (size_t)(_o + gk0), ldsK0 + 16*1024);                  \
    gload16(Kl + (size_t)(_o + gk1), ldsK1 + 16*1024);                  \
    gload16(Vt + (size_t)(gv0 + (kv0_)), ldsK0 + 32*1024);              \
    gload16(Vt + (size_t)(gv1 + (kv0_)), ldsK1 + 32*1024);              \
  } while(0)

  STAGE(kvbase);
  __syncthreads();

  f32x4 o[8] = {};
  float m_run = -3.0e38f, l_run = 0.f;

  for (int t = 0; t < NT; ++t){
    // ---- S^T = K·Q^T (hh + lh + hl)
    f32x4 s[4] = {};
    __builtin_amdgcn_s_setprio(1);
    #pragma unroll
    for (int nf = 0; nf < 4; ++nf){
      const int row = nf*16 + l15;
      const unsigned rbase = (unsigned)row*256u;
      const unsigned sw = (unsigned)(row & 7);
      #pragma unroll
      for (int kc = 0; kc < 4; ++kc){
        unsigned boff = rbase + ((((unsigned)(kc*4 + lk)) ^ sw)*16u);
        bf16x8 khf = *(const bf16x8*)(const void*)(smem + boff);
        bf16x8 klf = *(const bf16x8*)(const void*)(smem + 16*1024 + boff);
        s[nf] = __builtin_amdgcn_mfma_f32_16x16x32_bf16(khf, qh[kc], s[nf], 0,0,0);
        s[nf] = __builtin_amdgcn_mfma_f32_16x16x32_bf16(klf, qh[kc], s[nf], 0,0,0);
        s[nf] = __builtin_amdgcn_mfma_f32_16x16x32_bf16(khf, ql[kc], s[nf], 0,0,0);
      }
    }
    __builtin_amdgcn_s_setprio(0);

    // ---- online softmax: lane holds 16 logits (kv = nf*16+lk*4+r) for q = q0+l15
    float mx = fmaxf(fmaxf(s[0][0], s[0][1]), fmaxf(s[0][2], s[0][3]));
    #pragma unroll
    for (int nf = 1; nf < 4; ++nf)
      mx = fmaxf(mx, fmaxf(fmaxf(s[nf][0], s[nf][1]), fmaxf(s[nf][2], s[nf][3])));
    mx = fmaxf(mx, __shfl_xor(mx, 16));
    mx = fmaxf(mx, __shfl_xor(mx, 32));
    float mnew = fmaxf(m_run, mx);
    float corr = __expf(m_run - mnew);
    float tsum = 0.f;
    #pragma unroll
    for (int nf = 0; nf < 4; ++nf){
      u16x4 pk;
      #pragma unroll
      for (int r = 0; r < 4; ++r){
        float p = __expf(s[nf][r] - mnew);
        tsum += p;
        pk[r] = f2bf(p);
      }
      // P[q=l15][kv=nf*16+lk*4 ..+3], 8B-chunk swizzle: c8' = c8 ^ (2*(l15&7))
      *(u16x4*)(void*)(Pbase + l15*128 + (((unsigned)(nf*4 + lk)) ^ (2u*(unsigned)(l15 & 7)))*8u) = pk;
    }
    tsum += __shfl_xor(tsum, 16);
    tsum += __shfl_xor(tsum, 32);
    m_run = mnew;
    l_run = l_run*corr + tsum;
    #pragma unroll
    for (int nd = 0; nd < 8; ++nd) o[nd] *= corr;

    // ---- O^T += V^T · P^T
    __builtin_amdgcn_s_setprio(1);
    #pragma unroll
    for (int kc2 = 0; kc2 < 2; ++kc2){
      bf16x8 pf = *(const bf16x8*)(const void*)(Pbase + l15*128 +
                    ((((unsigned)(kc2*4 + lk)) ^ (unsigned)(l15 & 7))*16u));
      #pragma unroll
      for (int nd = 0; nd < 8; ++nd){
        const int row = nd*16 + l15;
        unsigned boff = 32u*1024u + (unsigned)row*128u +
                        ((((unsigned)(kc2*4 + lk)) ^ (unsigned)(row & 7))*16u);
        bf16x8 vf = *(const bf16x8*)(const void*)(smem + boff);
        o[nd] = __builtin_amdgcn_mfma_f32_16x16x32_bf16(vf, pf, o[nd], 0,0,0);
      }
    }
    __builtin_amdgcn_s_setprio(0);

    __syncthreads();                       // all waves done reading this tile
    if (t + 1 < NT) STAGE(kvbase + (t+1)*KVB);
    __syncthreads();                       // vmcnt(0) drain -> next tile visible
  }
  #undef STAGE

  // ---- epilogue: unnormalized O^T fragments -> Opart[q][d]
  float* Op = Opart + ((size_t)ks*NTOK + q0 + l15)*DH;
  #pragma unroll
  for (int nd = 0; nd < 8; ++nd)
    *(f32x4*)(Op + nd*16 + lk*4) = o[nd];
  if (lk == 0){
    mpart[(size_t)ks*NTOK + q0 + l15] = m_run;
    lpart[(size_t)ks*NTOK + q0 + l15] = l_run;
  }
}

// ---------- kernel 4: merge ksplit partials. grid NTOK*32/256, 256 thr.
__global__ void k_merge(const float* __restrict__ Opart, const float* __restrict__ mpart,
                        const float* __restrict__ lpart, float* __restrict__ out, int ksplit){
  int gid = blockIdx.x*256 + threadIdx.x;   // NTOK*32
  int n = gid >> 5, c4 = (gid & 31) * 4;
  float M = -1e30f;
  for (int ks = 0; ks < ksplit; ++ks) M = fmaxf(M, mpart[(size_t)ks*NTOK + n]);
  float L = 0.f;
  f32x4 acc = {0.f, 0.f, 0.f, 0.f};
  for (int ks = 0; ks < ksplit; ++ks){
    float w = __expf(mpart[(size_t)ks*NTOK + n] - M);
    L += lpart[(size_t)ks*NTOK + n] * w;
    f32x4 op = *(const f32x4*)(Opart + ((size_t)ks*NTOK + n)*DH + c4);
    acc += op * w;
  }
  float inv = 1.f / L;
  *(f32x4*)(out + (size_t)n*DH + c4) = acc * inv;
}

extern "C" void kernel_launch(void* const* d_in, const int* in_sizes, int n_in,
                              void* d_out, int out_size, void* d_ws, size_t ws_size,
                              hipStream_t stream){
  const float* x  = (const float*)d_in[0];
  const float* Wq = (const float*)d_in[1];
  const float* Wk = (const float*)d_in[2];
  const float* Wv = (const float*)d_in[3];
  float* out = (float*)d_out;

  char* ws = (char*)d_ws;
  const size_t SZ_WT = (size_t)384*1024*2;        // 768 KB
  const size_t SZ_X  = (size_t)NTOK*DIN*2;        // 16.78 MB
  const size_t SZ_QK = (size_t)NTOK*DH*2;         // 2 MB
  size_t off = 0;
  unsigned short* WhT = (unsigned short*)(ws + off); off += SZ_WT;
  unsigned short* WlT = (unsigned short*)(ws + off); off += SZ_WT;
  unsigned short* xh  = (unsigned short*)(ws + off); off += SZ_X;
  unsigned short* xl  = (unsigned short*)(ws + off); off += SZ_X;
  unsigned short* Qh  = (unsigned short*)(ws + off); off += SZ_QK;
  unsigned short* Ql  = (unsigned short*)(ws + off); off += SZ_QK;
  unsigned short* Kh  = (unsigned short*)(ws + off); off += SZ_QK;
  unsigned short* Kl  = (unsigned short*)(ws + off); off += SZ_QK;
  unsigned short* Vt  = (unsigned short*)(ws + off); off += SZ_QK;

  int ksplit = 8;
  while (ksplit > 1 &&
         off + (size_t)ksplit*(NTOK*(size_t)DH*4 + 2*NTOK*4) > ws_size)
    ksplit >>= 1;
  float* Opart = (float*)(ws + off); off += (size_t)ksplit*NTOK*DH*4;
  float* mpart = (float*)(ws + off); off += (size_t)ksplit*NTOK*4;
  float* lpart = (float*)(ws + off); off += (size_t)ksplit*NTOK*4;

  k_wsplit<<<dim3((384*1024)/256), dim3(256), 0, stream>>>(Wq, Wk, Wv, WhT, WlT);
  k_xsplit<<<dim3((NTOK*DIN)/(256*8)), dim3(256), 0, stream>>>(x, xh, xl);
  k_proj  <<<dim3(NTOK/64, 3), dim3(256), 0, stream>>>(xh, xl, WhT, WlT, Qh, Ql, Kh, Kl, Vt);
  k_flash <<<dim3((NTOK/128)*ksplit), dim3(512), 0, stream>>>(Qh, Ql, Kh, Kl, Vt,
                                                              Opart, mpart, lpart, ksplit);
  k_merge <<<dim3(NTOK*32/256), dim3(256), 0, stream>>>(Opart, mpart, lpart, out, ksplit);
}

// Round 3
// 248.134 us; speedup vs baseline: 1.4681x; 1.0057x over previous
//
#include <hip/hip_runtime.h>
#include <cstdint>
#include <cstddef>

#define NTOK 8192
#define DIN  1024
#define DH   128
#define KVB  64

typedef __attribute__((ext_vector_type(4))) float f32x4;
typedef __bf16 bf16x8 __attribute__((ext_vector_type(8)));
typedef unsigned short u16x8 __attribute__((ext_vector_type(8)));
typedef unsigned short u16x4 __attribute__((ext_vector_type(4)));

__device__ __forceinline__ unsigned short f2bf(float f){
  union { float f; unsigned u; } x; x.f = f;
  unsigned r = x.u + 0x7FFFu + ((x.u >> 16) & 1u);
  return (unsigned short)(r >> 16);
}
__device__ __forceinline__ float bf2f(unsigned short b){
  union { unsigned u; float f; } x; x.u = ((unsigned)b) << 16;
  return x.f;
}
// async global->LDS, 16B per lane. LDS dest = wave-uniform base + lane*16 (HW).
__device__ __forceinline__ void gload16(const void* g, void* l){
  using gp_t = const __attribute__((address_space(1))) char*;
  using lp_t = __attribute__((address_space(3))) char*;
  __builtin_amdgcn_global_load_lds((gp_t)(uintptr_t)g, (lp_t)(uint32_t)(uintptr_t)l, 16, 0, 0);
}

// ---------- kernel 1: split W into hi/lo bf16, transposed to [384][1024]
__global__ void k_wsplit(const float* __restrict__ Wq, const float* __restrict__ Wk,
                         const float* __restrict__ Wv,
                         unsigned short* __restrict__ WhT, unsigned short* __restrict__ WlT){
  int e = blockIdx.x * 256 + threadIdx.x;   // 384*1024 threads
  int n = e >> 10, k = e & 1023;
  const float* W = (n < 128) ? Wq : ((n < 256) ? Wk : Wv);
  float v = W[(size_t)k * 128 + (n & 127)];
  unsigned short h = f2bf(v);
  WhT[e] = h;
  WlT[e] = f2bf(v - bf2f(h));
}

// ---------- kernel 1b: split x into hi/lo bf16 (row-major [8192][1024])
__global__ void k_xsplit(const float* __restrict__ x,
                         unsigned short* __restrict__ xh, unsigned short* __restrict__ xl){
  size_t i = ((size_t)blockIdx.x * 256 + threadIdx.x) * 8;
  f32x4 a = *(const f32x4*)(x + i);
  f32x4 b = *(const f32x4*)(x + i + 4);
  u16x8 h, l;
  #pragma unroll
  for (int j = 0; j < 4; ++j){
    unsigned short h0 = f2bf(a[j]); h[j] = h0;   l[j]   = f2bf(a[j] - bf2f(h0));
    unsigned short h1 = f2bf(b[j]); h[4+j] = h1; l[4+j] = f2bf(b[j] - bf2f(h1));
  }
  *(u16x8*)(xh + i) = h;
  *(u16x8*)(xl + i) = l;
}

// ---------- kernel 2: QKV projection (bf16x2 MFMA). grid (256,3), 256 thr.
// BM=32: block = 32 rows x 128 cols of one of Q/K/V. Each wave: 32m x 32n.
// Fully-unrolled K-loop: compiler software-pipelines the 8 loads/iter.
__global__ __launch_bounds__(256, 3) void k_proj(
    const unsigned short* __restrict__ xh, const unsigned short* __restrict__ xl,
    const unsigned short* __restrict__ WhT, const unsigned short* __restrict__ WlT,
    unsigned short* __restrict__ Qh, unsigned short* __restrict__ Ql,
    unsigned short* __restrict__ Kh, unsigned short* __restrict__ Kl,
    unsigned short* __restrict__ Vt){
  const int lane = threadIdx.x & 63, wid = threadIdx.x >> 6;
  const int l15 = lane & 15, lk = lane >> 4;
  const int bm = blockIdx.x, bt = blockIdx.y;   // bt: 0=Q 1=K 2=V

  f32x4 acc[2][2] = {};

  const unsigned short* Ah = xh + (size_t)(bm*32 + l15) * DIN + lk*8;
  const unsigned short* Al = xl + (size_t)(bm*32 + l15) * DIN + lk*8;
  const unsigned short* Bh = WhT + (size_t)(bt*128 + wid*32 + l15) * DIN + lk*8;
  const unsigned short* Bl = WlT + (size_t)(bt*128 + wid*32 + l15) * DIN + lk*8;

  #pragma unroll
  for (int kc = 0; kc < DIN/32; ++kc){
    bf16x8 ah0 = *(const bf16x8*)(const void*)(Ah + kc*32);
    bf16x8 ah1 = *(const bf16x8*)(const void*)(Ah + (size_t)16*DIN + kc*32);
    bf16x8 al0 = *(const bf16x8*)(const void*)(Al + kc*32);
    bf16x8 al1 = *(const bf16x8*)(const void*)(Al + (size_t)16*DIN + kc*32);
    bf16x8 bh0 = *(const bf16x8*)(const void*)(Bh + kc*32);
    bf16x8 bh1 = *(const bf16x8*)(const void*)(Bh + (size_t)16*DIN + kc*32);
    bf16x8 bl0 = *(const bf16x8*)(const void*)(Bl + kc*32);
    bf16x8 bl1 = *(const bf16x8*)(const void*)(Bl + (size_t)16*DIN + kc*32);
    acc[0][0] = __builtin_amdgcn_mfma_f32_16x16x32_bf16(ah0, bh0, acc[0][0], 0,0,0);
    acc[0][0] = __builtin_amdgcn_mfma_f32_16x16x32_bf16(ah0, bl0, acc[0][0], 0,0,0);
    acc[0][0] = __builtin_amdgcn_mfma_f32_16x16x32_bf16(al0, bh0, acc[0][0], 0,0,0);
    acc[0][1] = __builtin_amdgcn_mfma_f32_16x16x32_bf16(ah0, bh1, acc[0][1], 0,0,0);
    acc[0][1] = __builtin_amdgcn_mfma_f32_16x16x32_bf16(ah0, bl1, acc[0][1], 0,0,0);
    acc[0][1] = __builtin_amdgcn_mfma_f32_16x16x32_bf16(al0, bh1, acc[0][1], 0,0,0);
    acc[1][0] = __builtin_amdgcn_mfma_f32_16x16x32_bf16(ah1, bh0, acc[1][0], 0,0,0);
    acc[1][0] = __builtin_amdgcn_mfma_f32_16x16x32_bf16(ah1, bl0, acc[1][0], 0,0,0);
    acc[1][0] = __builtin_amdgcn_mfma_f32_16x16x32_bf16(al1, bh0, acc[1][0], 0,0,0);
    acc[1][1] = __builtin_amdgcn_mfma_f32_16x16x32_bf16(ah1, bh1, acc[1][1], 0,0,0);
    acc[1][1] = __builtin_amdgcn_mfma_f32_16x16x32_bf16(ah1, bl1, acc[1][1], 0,0,0);
    acc[1][1] = __builtin_amdgcn_mfma_f32_16x16x32_bf16(al1, bh1, acc[1][1], 0,0,0);
  }

  const float qscale = 0.08838834764831845f;  // 1/sqrt(128), folded into Q
  #pragma unroll
  for (int mf = 0; mf < 2; ++mf){
    #pragma unroll
    for (int nf = 0; nf < 2; ++nf){
      #pragma unroll
      for (int r = 0; r < 4; ++r){
        int row = bm*32 + mf*16 + lk*4 + r;
        int col = wid*32 + nf*16 + l15;
        float v = acc[mf][nf][r];
        if (bt == 0){
          v *= qscale;
          unsigned short h = f2bf(v);
          Qh[(size_t)row*DH + col] = h;
          Ql[(size_t)row*DH + col] = f2bf(v - bf2f(h));
        } else if (bt == 1){
          unsigned short h = f2bf(v);
          Kh[(size_t)row*DH + col] = h;
          Kl[(size_t)row*DH + col] = f2bf(v - bf2f(h));
        } else {
          Vt[(size_t)col*NTOK + row] = f2bf(v);   // V^T [128][8192]
        }
      }
    }
  }
}

// ---------- kernel 3: flash attention partials.
// 512 thr = 8 waves, each wave owns 16 q rows (BM=128). KVB=64.
// LDS 64KB: Kh[64][128]swz | Kl | Vt[128][64]swz | P[8][16][64]swz
// Swapped QK^T: S^T = K·Q^T, lane = one q column (l15), kv in-lane.
__global__ __launch_bounds__(512, 4) void k_flash(
    const unsigned short* __restrict__ Qh, const unsigned short* __restrict__ Ql,
    const unsigned short* __restrict__ Kh, const unsigned short* __restrict__ Kl,
    const unsigned short* __restrict__ Vt,
    float* __restrict__ Opart, float* __restrict__ mpart, float* __restrict__ lpart,
    int ksplit){
  __shared__ __align__(16) char smem[65536];
  const int tid = threadIdx.x;
  const int lane = tid & 63, wid = tid >> 6;
  const int l15 = lane & 15, lk = lane >> 4;
  const int qb = blockIdx.x / ksplit, ks = blockIdx.x - qb*ksplit;
  const int q0 = qb*128 + wid*16;
  const int kvlen = NTOK / ksplit;
  const int kvbase = ks * kvlen;
  const int NT = kvlen / KVB;

  char* Pbase = smem + 48*1024 + wid*2048;   // per-wave P [16][64] bf16, swizzled

  // Q fragments (B-operand): lane holds Q[q0+l15][kc*32+lk*8 .. +7]
  bf16x8 qh[4], ql[4];
  #pragma unroll
  for (int kc = 0; kc < 4; ++kc){
    size_t off = (size_t)(q0 + l15)*DH + kc*32 + lk*8;
    qh[kc] = *(const bf16x8*)(const void*)(Qh + off);
    ql[kc] = *(const bf16x8*)(const void*)(Ql + off);
  }

  // staging: wave w stages chunks 2w,2w+1 of each of Kh,Kl,Vt (1KB each).
  // K chunk i covers rows 4i..4i+3 of [64][128]; lane -> row 4i+(lane>>4), slot lane&15,
  //   fetches global chunk cg = slot ^ (row&7)  (inverse swizzle at source).
  const int i0 = 2*wid, i1 = 2*wid + 1;
  int rk0 = 4*i0 + (lane >> 4), rk1 = 4*i1 + (lane >> 4);
  int gk0 = rk0*DH + ((lane & 15) ^ (rk0 & 7))*8;
  int gk1 = rk1*DH + ((lane & 15) ^ (rk1 & 7))*8;
  // V chunk i covers rows 8i..8i+7 of [128][64]; lane -> row 8i+(lane>>3), slot lane&7
  int rv0 = 8*i0 + (lane >> 3), rv1 = 8*i1 + (lane >> 3);
  int gv0 = rv0*NTOK + ((lane & 7) ^ (rv0 & 7))*8;
  int gv1 = rv1*NTOK + ((lane & 7) ^ (rv1 & 7))*8;
  char* ldsK0 = smem + i0*1024;
  char* ldsK1 = smem + i1*1024;

  #define STAGE(kv0_) do {                                              \
    int _o = (kv0_)*DH;                                                 \
    gload16(Kh + (size_t)(_o + gk0), ldsK0);                            \
    gload16(Kh + (size_t)(_o + gk1), ldsK1);                            \
    gload16(Kl + (size_t)(_o + gk0), ldsK0 + 16*1024);                  \
    gload16(Kl + (size_t)(_o + gk1), ldsK1 + 16*1024);                  \
    gload16(Vt + (size_t)(gv0 + (kv0_)), ldsK0 + 32*1024);              \
    gload16(Vt + (size_t)(gv1 + (kv0_)), ldsK1 + 32*1024);              \
  } while(0)

  STAGE(kvbase);
  __syncthreads();

  f32x4 o[8] = {};
  float m_run = -3.0e38f, l_run = 0.f;

  for (int t = 0; t < NT; ++t){
    // ---- S^T = K·Q^T (hh + lh + hl)
    f32x4 s[4] = {};
    __builtin_amdgcn_s_setprio(1);
    #pragma unroll
    for (int nf = 0; nf < 4; ++nf){
      const int row = nf*16 + l15;
      const unsigned rbase = (unsigned)row*256u;
      const unsigned sw = (unsigned)(row & 7);
      #pragma unroll
      for (int kc = 0; kc < 4; ++kc){
        unsigned boff = rbase + ((((unsigned)(kc*4 + lk)) ^ sw)*16u);
        bf16x8 khf = *(const bf16x8*)(const void*)(smem + boff);
        bf16x8 klf = *(const bf16x8*)(const void*)(smem + 16*1024 + boff);
        s[nf] = __builtin_amdgcn_mfma_f32_16x16x32_bf16(khf, qh[kc], s[nf], 0,0,0);
        s[nf] = __builtin_amdgcn_mfma_f32_16x16x32_bf16(klf, qh[kc], s[nf], 0,0,0);
        s[nf] = __builtin_amdgcn_mfma_f32_16x16x32_bf16(khf, ql[kc], s[nf], 0,0,0);
      }
    }
    __builtin_amdgcn_s_setprio(0);

    // ---- online softmax: lane holds 16 logits (kv = nf*16+lk*4+r) for q = q0+l15
    float mx = fmaxf(fmaxf(s[0][0], s[0][1]), fmaxf(s[0][2], s[0][3]));
    #pragma unroll
    for (int nf = 1; nf < 4; ++nf)
      mx = fmaxf(mx, fmaxf(fmaxf(s[nf][0], s[nf][1]), fmaxf(s[nf][2], s[nf][3])));
    mx = fmaxf(mx, __shfl_xor(mx, 16));
    mx = fmaxf(mx, __shfl_xor(mx, 32));
    float mnew = fmaxf(m_run, mx);
    float corr = __expf(m_run - mnew);
    float tsum = 0.f;
    #pragma unroll
    for (int nf = 0; nf < 4; ++nf){
      u16x4 pk;
      #pragma unroll
      for (int r = 0; r < 4; ++r){
        float p = __expf(s[nf][r] - mnew);
        tsum += p;
        pk[r] = f2bf(p);
      }
      // P[q=l15][kv=nf*16+lk*4 ..+3], 8B-chunk swizzle: c8' = c8 ^ (2*(l15&7))
      *(u16x4*)(void*)(Pbase + l15*128 + (((unsigned)(nf*4 + lk)) ^ (2u*(unsigned)(l15 & 7)))*8u) = pk;
    }
    tsum += __shfl_xor(tsum, 16);
    tsum += __shfl_xor(tsum, 32);
    m_run = mnew;
    l_run = l_run*corr + tsum;
    #pragma unroll
    for (int nd = 0; nd < 8; ++nd) o[nd] *= corr;

    // ---- O^T += V^T · P^T
    __builtin_amdgcn_s_setprio(1);
    #pragma unroll
    for (int kc2 = 0; kc2 < 2; ++kc2){
      bf16x8 pf = *(const bf16x8*)(const void*)(Pbase + l15*128 +
                    ((((unsigned)(kc2*4 + lk)) ^ (unsigned)(l15 & 7))*16u));
      #pragma unroll
      for (int nd = 0; nd < 8; ++nd){
        const int row = nd*16 + l15;
        unsigned boff = 32u*1024u + (unsigned)row*128u +
                        ((((unsigned)(kc2*4 + lk)) ^ (unsigned)(row & 7))*16u);
        bf16x8 vf = *(const bf16x8*)(const void*)(smem + boff);
        o[nd] = __builtin_amdgcn_mfma_f32_16x16x32_bf16(vf, pf, o[nd], 0,0,0);
      }
    }
    __builtin_amdgcn_s_setprio(0);

    __syncthreads();                       // all waves done reading this tile
    if (t + 1 < NT) STAGE(kvbase + (t+1)*KVB);
    __syncthreads();                       // vmcnt(0) drain -> next tile visible
  }
  #undef STAGE

  // ---- epilogue: unnormalized O^T fragments -> Opart[q][d]
  float* Op = Opart + ((size_t)ks*NTOK + q0 + l15)*DH;
  #pragma unroll
  for (int nd = 0; nd < 8; ++nd)
    *(f32x4*)(Op + nd*16 + lk*4) = o[nd];
  if (lk == 0){
    mpart[(size_t)ks*NTOK + q0 + l15] = m_run;
    lpart[(size_t)ks*NTOK + q0 + l15] = l_run;
  }
}

// ---------- kernel 4: merge ksplit partials. grid NTOK*32/256, 256 thr.
__global__ void k_merge(const float* __restrict__ Opart, const float* __restrict__ mpart,
                        const float* __restrict__ lpart, float* __restrict__ out, int ksplit){
  int gid = blockIdx.x*256 + threadIdx.x;   // NTOK*32
  int n = gid >> 5, c4 = (gid & 31) * 4;
  float M = -1e30f;
  for (int ks = 0; ks < ksplit; ++ks) M = fmaxf(M, mpart[(size_t)ks*NTOK + n]);
  float L = 0.f;
  f32x4 acc = {0.f, 0.f, 0.f, 0.f};
  for (int ks = 0; ks < ksplit; ++ks){
    float w = __expf(mpart[(size_t)ks*NTOK + n] - M);
    L += lpart[(size_t)ks*NTOK + n] * w;
    f32x4 op = *(const f32x4*)(Opart + ((size_t)ks*NTOK + n)*DH + c4);
    acc += op * w;
  }
  float inv = 1.f / L;
  *(f32x4*)(out + (size_t)n*DH + c4) = acc * inv;
}

extern "C" void kernel_launch(void* const* d_in, const int* in_sizes, int n_in,
                              void* d_out, int out_size, void* d_ws, size_t ws_size,
                              hipStream_t stream){
  const float* x  = (const float*)d_in[0];
  const float* Wq = (const float*)d_in[1];
  const float* Wk = (const float*)d_in[2];
  const float* Wv = (const float*)d_in[3];
  float* out = (float*)d_out;

  char* ws = (char*)d_ws;
  const size_t SZ_WT = (size_t)384*1024*2;        // 768 KB
  const size_t SZ_X  = (size_t)NTOK*DIN*2;        // 16.78 MB
  const size_t SZ_QK = (size_t)NTOK*DH*2;         // 2 MB
  size_t off = 0;
  unsigned short* WhT = (unsigned short*)(ws + off); off += SZ_WT;
  unsigned short* WlT = (unsigned short*)(ws + off); off += SZ_WT;
  unsigned short* xh  = (unsigned short*)(ws + off); off += SZ_X;
  unsigned short* xl  = (unsigned short*)(ws + off); off += SZ_X;
  unsigned short* Qh  = (unsigned short*)(ws + off); off += SZ_QK;
  unsigned short* Ql  = (unsigned short*)(ws + off); off += SZ_QK;
  unsigned short* Kh  = (unsigned short*)(ws + off); off += SZ_QK;
  unsigned short* Kl  = (unsigned short*)(ws + off); off += SZ_QK;
  unsigned short* Vt  = (unsigned short*)(ws + off); off += SZ_QK;

  int ksplit = 8;
  while (ksplit > 1 &&
         off + (size_t)ksplit*(NTOK*(size_t)DH*4 + 2*NTOK*4) > ws_size)
    ksplit >>= 1;
  float* Opart = (float*)(ws + off); off += (size_t)ksplit*NTOK*DH*4;
  float* mpart = (float*)(ws + off); off += (size_t)ksplit*NTOK*4;
  float* lpart = (float*)(ws + off); off += (size_t)ksplit*NTOK*4;

  k_wsplit<<<dim3((384*1024)/256), dim3(256), 0, stream>>>(Wq, Wk, Wv, WhT, WlT);
  k_xsplit<<<dim3((NTOK*DIN)/(256*8)), dim3(256), 0, stream>>>(x, xh, xl);
  k_proj  <<<dim3(NTOK/32, 3), dim3(256), 0, stream>>>(xh, xl, WhT, WlT, Qh, Ql, Kh, Kl, Vt);
  k_flash <<<dim3((NTOK/128)*ksplit), dim3(512), 0, stream>>>(Qh, Ql, Kh, Kl, Vt,
                                                              Opart, mpart, lpart, ksplit);
  k_merge <<<dim3(NTOK*32/256), dim3(256), 0, stream>>>(Opart, mpart, lpart, out, ksplit);
}

// Round 4
// 181.635 us; speedup vs baseline: 2.0056x; 1.3661x over previous
//
#include <hip/hip_runtime.h>
#include <cstdint>
#include <cstddef>

#define NTOK 8192
#define DIN  1024
#define DH   128
#define KVB  64

typedef __attribute__((ext_vector_type(4))) float f32x4;
typedef __bf16 bf16x8 __attribute__((ext_vector_type(8)));
typedef unsigned short u16x8 __attribute__((ext_vector_type(8)));
typedef unsigned short u16x4 __attribute__((ext_vector_type(4)));

__device__ __forceinline__ unsigned short f2bf(float f){
  union { float f; unsigned u; } x; x.f = f;
  unsigned r = x.u + 0x7FFFu + ((x.u >> 16) & 1u);
  return (unsigned short)(r >> 16);
}
__device__ __forceinline__ float bf2f(unsigned short b){
  union { unsigned u; float f; } x; x.u = ((unsigned)b) << 16;
  return x.f;
}
// async global->LDS, 16B per lane. LDS dest = wave-uniform base + lane*16 (HW).
__device__ __forceinline__ void gload16(const void* g, void* l){
  using gp_t = const __attribute__((address_space(1))) char*;
  using lp_t = __attribute__((address_space(3))) char*;
  __builtin_amdgcn_global_load_lds((gp_t)(uintptr_t)g, (lp_t)(uint32_t)(uintptr_t)l, 16, 0, 0);
}

// ---------- kernel 1: split W into hi/lo bf16, transposed to [384][1024]
__global__ void k_wsplit(const float* __restrict__ Wq, const float* __restrict__ Wk,
                         const float* __restrict__ Wv,
                         unsigned short* __restrict__ WhT, unsigned short* __restrict__ WlT){
  int e = blockIdx.x * 256 + threadIdx.x;   // 384*1024 threads
  int n = e >> 10, k = e & 1023;
  const float* W = (n < 128) ? Wq : ((n < 256) ? Wk : Wv);
  float v = W[(size_t)k * 128 + (n & 127)];
  unsigned short h = f2bf(v);
  WhT[e] = h;
  WlT[e] = f2bf(v - bf2f(h));
}

// ---------- kernel 1b: split x into hi/lo bf16 (row-major [8192][1024])
__global__ void k_xsplit(const float* __restrict__ x,
                         unsigned short* __restrict__ xh, unsigned short* __restrict__ xl){
  size_t i = ((size_t)blockIdx.x * 256 + threadIdx.x) * 8;
  f32x4 a = *(const f32x4*)(x + i);
  f32x4 b = *(const f32x4*)(x + i + 4);
  u16x8 h, l;
  #pragma unroll
  for (int j = 0; j < 4; ++j){
    unsigned short h0 = f2bf(a[j]); h[j] = h0;   l[j]   = f2bf(a[j] - bf2f(h0));
    unsigned short h1 = f2bf(b[j]); h[4+j] = h1; l[4+j] = f2bf(b[j] - bf2f(h1));
  }
  *(u16x8*)(xh + i) = h;
  *(u16x8*)(xl + i) = l;
}

// ---------- kernel 2: QKV projection, m97-structure LDS-staged GEMM.
// grid (128, 6): by -> bt = by>>1 (0=Q 1=K 2=V), nh = by&1 (64-col half).
// Block: 64 rows x 64 cols. 4 waves 2x2, wave tile 32x32. BK=64, 16 K-steps.
// LDS 32KB: Ah | Al | Bh | Bl, each [64][64] bf16, XOR-swizzled 16B slots.
// Q/K: 3-product bf16x2 split; V: single hh product (error budget allows).
__global__ __launch_bounds__(256, 3) void k_proj(
    const unsigned short* __restrict__ xh, const unsigned short* __restrict__ xl,
    const unsigned short* __restrict__ WhT, const unsigned short* __restrict__ WlT,
    unsigned short* __restrict__ Qh, unsigned short* __restrict__ Ql,
    unsigned short* __restrict__ Kh, unsigned short* __restrict__ Kl,
    unsigned short* __restrict__ Vt){
  __shared__ __align__(16) char smem[32768];
  const int lane = threadIdx.x & 63, wid = threadIdx.x >> 6;
  const int l15 = lane & 15, lk = lane >> 4;
  const int bm = blockIdx.x;
  const int by = blockIdx.y;
  const int bt = by >> 1, nh = by & 1;
  const int wm = wid >> 1, wn = wid & 1;

  // ---- staging setup: wave w stages tile w (0:Ah 1:Al 2:Bh 3:Bl), 8 chunks of 1KB.
  // chunk i = rows 8i..8i+7; lane -> row 8i+(lane>>3), 16B slot lane&7,
  // global col-chunk = (lane&7) ^ (lane>>3)  (row&7 == lane>>3 always).
  const int srow = lane >> 3;
  const int gc8  = (lane & 7) ^ srow;
  const unsigned short* gsrc;
  char* ldst;
  int grow0;
  if (wid == 0){      gsrc = xh;  grow0 = bm*64;            ldst = smem; }
  else if (wid == 1){ gsrc = xl;  grow0 = bm*64;            ldst = smem + 8192; }
  else if (wid == 2){ gsrc = WhT; grow0 = bt*128 + nh*64;   ldst = smem + 16384; }
  else {              gsrc = WlT; grow0 = bt*128 + nh*64;   ldst = smem + 24576; }
  const unsigned short* gbase = gsrc + (size_t)(grow0 + srow)*DIN + gc8*8;
  const bool stage_on = (bt < 2) || (wid == 0) || (wid == 2);   // V skips lo tiles

  f32x4 acc[2][2] = {};

  for (int t = 0; t < 16; ++t){
    if (stage_on){
      #pragma unroll
      for (int i = 0; i < 8; ++i)
        gload16(gbase + (size_t)i*8*DIN + t*64, ldst + i*1024);
    }
    __syncthreads();   // vmcnt(0) drain + barrier: tile visible to all waves

    // ---- fragments from LDS (swizzled): row base A = wm*32, B = wn*32
    bf16x8 a_h[2][2], a_l[2][2], b_h[2][2], b_l[2][2];   // [mf|nf][kc]
    const unsigned sw = (unsigned)(l15 & 7);
    #pragma unroll
    for (int mf = 0; mf < 2; ++mf)
      #pragma unroll
      for (int kc = 0; kc < 2; ++kc){
        unsigned rA = (unsigned)(wm*32 + mf*16 + l15);
        unsigned offA = rA*128u + ((((unsigned)(kc*4 + lk)) ^ sw)*16u);
        a_h[mf][kc] = *(const bf16x8*)(const void*)(smem + offA);
        unsigned rB = (unsigned)(wn*32 + mf*16 + l15);
        unsigned offB = rB*128u + ((((unsigned)(kc*4 + lk)) ^ sw)*16u);
        b_h[mf][kc] = *(const bf16x8*)(const void*)(smem + 16384 + offB);
        if (bt < 2){
          a_l[mf][kc] = *(const bf16x8*)(const void*)(smem + 8192 + offA);
          b_l[mf][kc] = *(const bf16x8*)(const void*)(smem + 24576 + offB);
        }
      }
    #pragma unroll
    for (int mf = 0; mf < 2; ++mf)
      #pragma unroll
      for (int nf = 0; nf < 2; ++nf)
        #pragma unroll
        for (int kc = 0; kc < 2; ++kc){
          acc[mf][nf] = __builtin_amdgcn_mfma_f32_16x16x32_bf16(a_h[mf][kc], b_h[nf][kc], acc[mf][nf], 0,0,0);
          if (bt < 2){
            acc[mf][nf] = __builtin_amdgcn_mfma_f32_16x16x32_bf16(a_h[mf][kc], b_l[nf][kc], acc[mf][nf], 0,0,0);
            acc[mf][nf] = __builtin_amdgcn_mfma_f32_16x16x32_bf16(a_l[mf][kc], b_h[nf][kc], acc[mf][nf], 0,0,0);
          }
        }
    __syncthreads();   // all waves done reading before next stage overwrites
  }

  const float qscale = 0.08838834764831845f;  // 1/sqrt(128), folded into Q
  #pragma unroll
  for (int mf = 0; mf < 2; ++mf){
    #pragma unroll
    for (int nf = 0; nf < 2; ++nf){
      #pragma unroll
      for (int r = 0; r < 4; ++r){
        int row = bm*64 + wm*32 + mf*16 + lk*4 + r;
        int col = nh*64 + wn*32 + nf*16 + l15;
        float v = acc[mf][nf][r];
        if (bt == 0){
          v *= qscale;
          unsigned short h = f2bf(v);
          Qh[(size_t)row*DH + col] = h;
          Ql[(size_t)row*DH + col] = f2bf(v - bf2f(h));
        } else if (bt == 1){
          unsigned short h = f2bf(v);
          Kh[(size_t)row*DH + col] = h;
          Kl[(size_t)row*DH + col] = f2bf(v - bf2f(h));
        } else {
          Vt[(size_t)col*NTOK + row] = f2bf(v);   // V^T [128][8192]
        }
      }
    }
  }
}

// ---------- kernel 3: flash attention partials.
// 512 thr = 8 waves, each wave owns 16 q rows (BM=128). KVB=64.
// LDS 64KB: Kh[64][128]swz | Kl | Vt[128][64]swz | P[8][16][64]swz
// Swapped QK^T: S^T = K·Q^T, lane = one q column (l15), kv in-lane.
__global__ __launch_bounds__(512, 4) void k_flash(
    const unsigned short* __restrict__ Qh, const unsigned short* __restrict__ Ql,
    const unsigned short* __restrict__ Kh, const unsigned short* __restrict__ Kl,
    const unsigned short* __restrict__ Vt,
    float* __restrict__ Opart, float* __restrict__ mpart, float* __restrict__ lpart,
    int ksplit){
  __shared__ __align__(16) char smem[65536];
  const int tid = threadIdx.x;
  const int lane = tid & 63, wid = tid >> 6;
  const int l15 = lane & 15, lk = lane >> 4;
  const int qb = blockIdx.x / ksplit, ks = blockIdx.x - qb*ksplit;
  const int q0 = qb*128 + wid*16;
  const int kvlen = NTOK / ksplit;
  const int kvbase = ks * kvlen;
  const int NT = kvlen / KVB;

  char* Pbase = smem + 48*1024 + wid*2048;   // per-wave P [16][64] bf16, swizzled

  // Q fragments (B-operand): lane holds Q[q0+l15][kc*32+lk*8 .. +7]
  bf16x8 qh[4], ql[4];
  #pragma unroll
  for (int kc = 0; kc < 4; ++kc){
    size_t off = (size_t)(q0 + l15)*DH + kc*32 + lk*8;
    qh[kc] = *(const bf16x8*)(const void*)(Qh + off);
    ql[kc] = *(const bf16x8*)(const void*)(Ql + off);
  }

  // staging: wave w stages chunks 2w,2w+1 of each of Kh,Kl,Vt (1KB each).
  const int i0 = 2*wid, i1 = 2*wid + 1;
  int rk0 = 4*i0 + (lane >> 4), rk1 = 4*i1 + (lane >> 4);
  int gk0 = rk0*DH + ((lane & 15) ^ (rk0 & 7))*8;
  int gk1 = rk1*DH + ((lane & 15) ^ (rk1 & 7))*8;
  int rv0 = 8*i0 + (lane >> 3), rv1 = 8*i1 + (lane >> 3);
  int gv0 = rv0*NTOK + ((lane & 7) ^ (rv0 & 7))*8;
  int gv1 = rv1*NTOK + ((lane & 7) ^ (rv1 & 7))*8;
  char* ldsK0 = smem + i0*1024;
  char* ldsK1 = smem + i1*1024;

  #define STAGE(kv0_) do {                                              \
    int _o = (kv0_)*DH;                                                 \
    gload16(Kh + (size_t)(_o + gk0), ldsK0);                            \
    gload16(Kh + (size_t)(_o + gk1), ldsK1);                            \
    gload16(Kl + (size_t)(_o + gk0), ldsK0 + 16*1024);                  \
    gload16(Kl + (size_t)(_o + gk1), ldsK1 + 16*1024);                  \
    gload16(Vt + (size_t)(gv0 + (kv0_)), ldsK0 + 32*1024);              \
    gload16(Vt + (size_t)(gv1 + (kv0_)), ldsK1 + 32*1024);              \
  } while(0)

  STAGE(kvbase);
  __syncthreads();

  f32x4 o[8] = {};
  float m_run = -3.0e38f, l_run = 0.f;

  for (int t = 0; t < NT; ++t){
    // ---- S^T = K·Q^T (hh + lh + hl)
    f32x4 s[4] = {};
    __builtin_amdgcn_s_setprio(1);
    #pragma unroll
    for (int nf = 0; nf < 4; ++nf){
      const int row = nf*16 + l15;
      const unsigned rbase = (unsigned)row*256u;
      const unsigned sw = (unsigned)(row & 7);
      #pragma unroll
      for (int kc = 0; kc < 4; ++kc){
        unsigned boff = rbase + ((((unsigned)(kc*4 + lk)) ^ sw)*16u);
        bf16x8 khf = *(const bf16x8*)(const void*)(smem + boff);
        bf16x8 klf = *(const bf16x8*)(const void*)(smem + 16*1024 + boff);
        s[nf] = __builtin_amdgcn_mfma_f32_16x16x32_bf16(khf, qh[kc], s[nf], 0,0,0);
        s[nf] = __builtin_amdgcn_mfma_f32_16x16x32_bf16(klf, qh[kc], s[nf], 0,0,0);
        s[nf] = __builtin_amdgcn_mfma_f32_16x16x32_bf16(khf, ql[kc], s[nf], 0,0,0);
      }
    }
    __builtin_amdgcn_s_setprio(0);

    // ---- online softmax: lane holds 16 logits (kv = nf*16+lk*4+r) for q = q0+l15
    float mx = fmaxf(fmaxf(s[0][0], s[0][1]), fmaxf(s[0][2], s[0][3]));
    #pragma unroll
    for (int nf = 1; nf < 4; ++nf)
      mx = fmaxf(mx, fmaxf(fmaxf(s[nf][0], s[nf][1]), fmaxf(s[nf][2], s[nf][3])));
    mx = fmaxf(mx, __shfl_xor(mx, 16));
    mx = fmaxf(mx, __shfl_xor(mx, 32));
    float mnew = fmaxf(m_run, mx);
    float corr = __expf(m_run - mnew);
    float tsum = 0.f;
    #pragma unroll
    for (int nf = 0; nf < 4; ++nf){
      u16x4 pk;
      #pragma unroll
      for (int r = 0; r < 4; ++r){
        float p = __expf(s[nf][r] - mnew);
        tsum += p;
        pk[r] = f2bf(p);
      }
      *(u16x4*)(void*)(Pbase + l15*128 + (((unsigned)(nf*4 + lk)) ^ (2u*(unsigned)(l15 & 7)))*8u) = pk;
    }
    tsum += __shfl_xor(tsum, 16);
    tsum += __shfl_xor(tsum, 32);
    m_run = mnew;
    l_run = l_run*corr + tsum;
    #pragma unroll
    for (int nd = 0; nd < 8; ++nd) o[nd] *= corr;

    // ---- O^T += V^T · P^T
    __builtin_amdgcn_s_setprio(1);
    #pragma unroll
    for (int kc2 = 0; kc2 < 2; ++kc2){
      bf16x8 pf = *(const bf16x8*)(const void*)(Pbase + l15*128 +
                    ((((unsigned)(kc2*4 + lk)) ^ (unsigned)(l15 & 7))*16u));
      #pragma unroll
      for (int nd = 0; nd < 8; ++nd){
        const int row = nd*16 + l15;
        unsigned boff = 32u*1024u + (unsigned)row*128u +
                        ((((unsigned)(kc2*4 + lk)) ^ (unsigned)(row & 7))*16u);
        bf16x8 vf = *(const bf16x8*)(const void*)(smem + boff);
        o[nd] = __builtin_amdgcn_mfma_f32_16x16x32_bf16(vf, pf, o[nd], 0,0,0);
      }
    }
    __builtin_amdgcn_s_setprio(0);

    __syncthreads();                       // all waves done reading this tile
    if (t + 1 < NT) STAGE(kvbase + (t+1)*KVB);
    __syncthreads();                       // vmcnt(0) drain -> next tile visible
  }
  #undef STAGE

  // ---- epilogue: unnormalized O^T fragments -> Opart[q][d]
  float* Op = Opart + ((size_t)ks*NTOK + q0 + l15)*DH;
  #pragma unroll
  for (int nd = 0; nd < 8; ++nd)
    *(f32x4*)(Op + nd*16 + lk*4) = o[nd];
  if (lk == 0){
    mpart[(size_t)ks*NTOK + q0 + l15] = m_run;
    lpart[(size_t)ks*NTOK + q0 + l15] = l_run;
  }
}

// ---------- kernel 4: merge ksplit partials. grid NTOK*32/256, 256 thr.
__global__ void k_merge(const float* __restrict__ Opart, const float* __restrict__ mpart,
                        const float* __restrict__ lpart, float* __restrict__ out, int ksplit){
  int gid = blockIdx.x*256 + threadIdx.x;   // NTOK*32
  int n = gid >> 5, c4 = (gid & 31) * 4;
  float M = -1e30f;
  for (int ks = 0; ks < ksplit; ++ks) M = fmaxf(M, mpart[(size_t)ks*NTOK + n]);
  float L = 0.f;
  f32x4 acc = {0.f, 0.f, 0.f, 0.f};
  for (int ks = 0; ks < ksplit; ++ks){
    float w = __expf(mpart[(size_t)ks*NTOK + n] - M);
    L += lpart[(size_t)ks*NTOK + n] * w;
    f32x4 op = *(const f32x4*)(Opart + ((size_t)ks*NTOK + n)*DH + c4);
    acc += op * w;
  }
  float inv = 1.f / L;
  *(f32x4*)(out + (size_t)n*DH + c4) = acc * inv;
}

extern "C" void kernel_launch(void* const* d_in, const int* in_sizes, int n_in,
                              void* d_out, int out_size, void* d_ws, size_t ws_size,
                              hipStream_t stream){
  const float* x  = (const float*)d_in[0];
  const float* Wq = (const float*)d_in[1];
  const float* Wk = (const float*)d_in[2];
  const float* Wv = (const float*)d_in[3];
  float* out = (float*)d_out;

  char* ws = (char*)d_ws;
  const size_t SZ_WT = (size_t)384*1024*2;        // 768 KB
  const size_t SZ_X  = (size_t)NTOK*DIN*2;        // 16.78 MB
  const size_t SZ_QK = (size_t)NTOK*DH*2;         // 2 MB
  size_t off = 0;
  unsigned short* WhT = (unsigned short*)(ws + off); off += SZ_WT;
  unsigned short* WlT = (unsigned short*)(ws + off); off += SZ_WT;
  unsigned short* xh  = (unsigned short*)(ws + off); off += SZ_X;
  unsigned short* xl  = (unsigned short*)(ws + off); off += SZ_X;
  unsigned short* Qh  = (unsigned short*)(ws + off); off += SZ_QK;
  unsigned short* Ql  = (unsigned short*)(ws + off); off += SZ_QK;
  unsigned short* Kh  = (unsigned short*)(ws + off); off += SZ_QK;
  unsigned short* Kl  = (unsigned short*)(ws + off); off += SZ_QK;
  unsigned short* Vt  = (unsigned short*)(ws + off); off += SZ_QK;

  int ksplit = 8;
  while (ksplit > 1 &&
         off + (size_t)ksplit*(NTOK*(size_t)DH*4 + 2*NTOK*4) > ws_size)
    ksplit >>= 1;
  float* Opart = (float*)(ws + off); off += (size_t)ksplit*NTOK*DH*4;
  float* mpart = (float*)(ws + off); off += (size_t)ksplit*NTOK*4;
  float* lpart = (float*)(ws + off); off += (size_t)ksplit*NTOK*4;

  k_wsplit<<<dim3((384*1024)/256), dim3(256), 0, stream>>>(Wq, Wk, Wv, WhT, WlT);
  k_xsplit<<<dim3((NTOK*DIN)/(256*8)), dim3(256), 0, stream>>>(x, xh, xl);
  k_proj  <<<dim3(NTOK/64, 6), dim3(256), 0, stream>>>(xh, xl, WhT, WlT, Qh, Ql, Kh, Kl, Vt);
  k_flash <<<dim3((NTOK/128)*ksplit), dim3(512), 0, stream>>>(Qh, Ql, Kh, Kl, Vt,
                                                              Opart, mpart, lpart, ksplit);
  k_merge <<<dim3(NTOK*32/256), dim3(256), 0, stream>>>(Opart, mpart, lpart, out, ksplit);
}